// Round 8
// baseline (184.384 us; speedup 1.0000x reference)
//
#include <hip/hip_runtime.h>

// RickerCWT via f16 MFMA GEMM, symmetry-halved K (round 12):
//   out[b,s,t] = sum_{d=0..271} W'[s,d] * z[t,d],
//   z[t,d] = x[t+d] + x[t-d],  W'[s,d] = W[s,271+d],  W'[s,0] halved.
// NEW vs r11: (1) W' staged into LDS once per block via 34 block-cooperative
// global_load_lds dwordx4 issued BEFORE phase A (completes under the existing
// barriers; no extra sync). Rationale: wpk = 34.8KB > 32KB L1 -> cyclic
// streaming = ~100% L1 miss; all 1088 B-loads/CU were L2-latency-exposed
// (~200-400cy vs 32cy MFMA cover). NOT r8's mistake (per-wave 4x-redundant
// staging); this is classic single-copy block staging, K-loop has ZERO VMEM.
// (2) nontemporal epilogue stores: out (134MB write-once) no longer evicts
// the L2 working set. LDS 49.4KB -> 3 blocks/CU (12 waves/CU; r10 tied best
// at 8, TLP sufficient).
// - Wave tile 64t x 64s (2x2 frags mfma_f32_32x32x16_f16, 115 VGPR), TT=256,
//   grid 16x128 = 2048 blocks, lb(256,3).
// - z-frag: forward aligned ds_read_b128 (8-shifted-copy Hankel LDS) +
//   backward aligned ds_read_b128 + 8-elem reversal + v_pk_add_f16.
// - B-frag: wsm[1024*ks + 512*st + lane*8], stride-1 b128, conflict-free.

#define TLEN  4096
#define NSC   64
#define KLEN  543
#define PADL  271
#define BLOCK 256
#define TT    256            // t per block (4 waves x 64t)
#define XSRC  808            // raw staged x elems (101 short8)
#define XLEN  800            // per-copy slots (need 0..797)
#define XREG  808            // copy stride in elems (101*8, odd chunk stride)
#define NKS2  17             // K-steps of 16 over d=0..271
#define WPK_N (NKS2 * 2 * 64 * 8)   // 17408 f16 elems = 34 KB = 34 segments

typedef __attribute__((ext_vector_type(8)))  short     short8;
typedef __attribute__((ext_vector_type(8)))  _Float16  half8;
typedef __attribute__((ext_vector_type(16))) float     float16v;
typedef __attribute__((ext_vector_type(4)))  float     float4v;

__global__ __launch_bounds__(256)
void wconv(const float* __restrict__ W, _Float16* __restrict__ wpk)
{
    int idx  = blockIdx.x * 256 + threadIdx.x;    // 0..17407
    int e    = idx & 7;                           // elem within lane's 16B
    int lane = (idx >> 3) & 63;                   // hw lane order
    int st   = (idx >> 9) & 1;                    // s-frag (0: s<32, 1: s>=32)
    int ks   = idx >> 10;                         // K-step of 16 (0..16)
    int n    = lane & 31;
    int q5   = lane >> 5;
    int s    = 32 * st + n;
    int d    = 16 * ks + 8 * q5 + e;              // 0..271
    float v  = W[(size_t)s * KLEN + PADL + d];    // W'[s,d] = W[s,271+d]
    if (d == 0) v *= 0.5f;                        // absorb z[t,0] = 2*x[t]
    wpk[idx] = (_Float16)v;
}

__global__ __launch_bounds__(BLOCK, 3)
void ricker_mfma2(const float* __restrict__ x,
                  const _Float16* __restrict__ wpk,
                  float* __restrict__ out)
{
    __shared__ __align__(16) _Float16 xraw[XSRC];
    __shared__ __align__(16) _Float16 xsm[8 * XREG];   // 12928 B
    __shared__ __align__(16) _Float16 wsm[WPK_N];      // 34816 B

    const int tid    = threadIdx.x;
    const int lane   = tid & 63;
    const int wv     = tid >> 6;          // 0..3
    const int tTile  = blockIdx.x;        // 0..15
    const int b      = blockIdx.y;        // 0..127
    const int tStart = tTile * TT;

    // ---- stage W' -> LDS, block-cooperative, async (lands by barrier 2) ----
    // 34 x global_load_lds dwordx4: wave wv issues segments wv, wv+4, ...
    // Each segment: lane l copies wpk[j*512 + l*8 .. +7] -> wsm[j*512 + l*8].
    for (int j = wv; j < 2 * NKS2; j += 4) {
        __builtin_amdgcn_global_load_lds(
            (const __attribute__((address_space(1))) void*)(wpk + j * 512 + lane * 8),
            (__attribute__((address_space(3))) void*)&wsm[j * 512],
            16, 0, 0);
    }

    // ---- phase A: raw f16 x tile (halo, zero-padded), coalesced ----
    const float* xrow = x + (size_t)b * TLEN;
    for (int i = tid; i < XSRC; i += BLOCK) {
        int g = tStart - PADL + i;
        float v = (g >= 0 && g < TLEN) ? xrow[g] : 0.0f;
        xraw[i] = (_Float16)v;
    }
    __syncthreads();

    // ---- phase B: 8 shifted copies, vectorized b128 (shift c compile-time) --
    // xsm[c*XREG + p] = xraw[p + c], p in [0, XLEN), c in [0,8).
    {
        const short8* xr8 = (const short8*)xraw;
        short8*       xs8 = (short8*)xsm;
        for (int j = tid; j < 100; j += BLOCK) {      // one predicated pass
            short8 lo = xr8[j];
            short8 hi = xr8[j + 1];
            #pragma unroll
            for (int c = 0; c < 8; ++c) {
                short8 r;
                #pragma unroll
                for (int e = 0; e < 8; ++e)
                    r[e] = (c + e < 8) ? lo[c + e] : hi[c + e - 8];
                xs8[c * 101 + j] = r;                 // == xsm[c*XREG + 8j]
            }
        }
    }
    // drain W staging (explicit; compiler would fold into barrier anyway)
    asm volatile("s_waitcnt vmcnt(0)" ::: "memory");
    __syncthreads();

    // ---- wave GEMM: 64t x 64s, mfma_f32_32x32x16_f16, 2x2 frags ----
    const int n    = lane & 31;       // A row m / B col n / D col (s)
    const int q5   = lane >> 5;       // k-half
    const int wt0  = wv * 64;

    // Forward slab: f[j] = x[t+d0+j] = xraw[tau + 271 + d0 + j],
    //   tau = wt0+32tt+n, d0 = 16ks+8q5.  Start S_f = tau+271+d0:
    //   copy cf = (n+7)&7, in-copy slot = wt0+8q5+(n+271-cf) + 16ks+32tt.
    // Backward slab: r[e] = xraw[tau + 264 - d0 + e]  (rev(r)[j]=x[t-d0-j]):
    //   copy cr = n&7,     in-copy slot = wt0-8q5+264+(n-cr) - 16ks+32tt.
    const int cf = (n + 7) & 7;
    const int cr = n & 7;
    const _Float16* af = &xsm[cf * XREG + wt0 + 8 * q5 + (n + PADL - cf)];
    const _Float16* ar = &xsm[cr * XREG + wt0 - 8 * q5 + 264 + (n - cr)];
    // B-frag: per-(ks,st) 1KB LDS block, lane-ordered stride-1 (conflict-free)
    const _Float16* bbase = wsm + lane * 8;

    float16v acc[2][2];
    #pragma unroll
    for (int tt = 0; tt < 2; ++tt)
        #pragma unroll
        for (int st = 0; st < 2; ++st)
            #pragma unroll
            for (int e = 0; e < 16; ++e) acc[tt][st][e] = 0.f;

    #pragma unroll 2
    for (int ks = 0; ks < NKS2; ++ks) {
        const int KF = 16 * ks;
        const int BO = 1024 * ks;                        // (ks*2)*512 elems
        half8 bb0 = *(const half8*)&bbase[BO];           // st=0
        half8 bb1 = *(const half8*)&bbase[BO + 512];     // st=1
        half8 z[2];
        #pragma unroll
        for (int tt = 0; tt < 2; ++tt) {
            half8 f = *(const half8*)&af[KF + 32 * tt];
            half8 r = *(const half8*)&ar[32 * tt - KF];
            half8 rv = __builtin_shufflevector(r, r, 7, 6, 5, 4, 3, 2, 1, 0);
            z[tt] = f + rv;                              // v_pk_add_f16 x4
        }
        #pragma unroll
        for (int tt = 0; tt < 2; ++tt) {
            acc[tt][0] = __builtin_amdgcn_mfma_f32_32x32x16_f16(z[tt], bb0, acc[tt][0], 0, 0, 0);
            acc[tt][1] = __builtin_amdgcn_mfma_f32_32x32x16_f16(z[tt], bb1, acc[tt][1], 0, 0, 0);
        }
    }

    // ---- epilogue: D col = n (s), row = (reg&3) + 8*(reg>>2) + 4*q5 (t) ----
    const int tb = tStart + wt0 + 4 * q5;
    float* obase = out + (size_t)b * NSC * TLEN;
    #pragma unroll
    for (int st = 0; st < 2; ++st) {
        #pragma unroll
        for (int tt = 0; tt < 2; ++tt) {
            float16v A = acc[tt][st];
            float* o = obase + (size_t)(32 * st + n) * TLEN + tb + 32 * tt;
            #pragma unroll
            for (int r4 = 0; r4 < 4; ++r4) {
                float4v v4 = {A[4 * r4], A[4 * r4 + 1], A[4 * r4 + 2], A[4 * r4 + 3]};
                __builtin_nontemporal_store(v4, (float4v*)&o[8 * r4]);
            }
        }
    }
}

extern "C" void kernel_launch(void* const* d_in, const int* in_sizes, int n_in,
                              void* d_out, int out_size, void* d_ws, size_t ws_size,
                              hipStream_t stream) {
    const float* x   = (const float*)d_in[0];   // [128, 4096] fp32
    const float* W   = (const float*)d_in[1];   // [64, 543]  fp32
    float*       out = (float*)d_out;           // [128, 64, 4096] fp32
    _Float16*    wpk = (_Float16*)d_ws;         // [17,2,64,8] f16 blocks (34,816 B)

    wconv<<<dim3(WPK_N / 256), dim3(256), 0, stream>>>(W, wpk);
    dim3 grid(TLEN / TT, 128);                  // (16, 128) = 2048 blocks
    ricker_mfma2<<<grid, dim3(BLOCK), 0, stream>>>(x, wpk, out);
}

// Round 9
// 155.739 us; speedup vs baseline: 1.1839x; 1.1839x over previous
//
#include <hip/hip_runtime.h>

// RickerCWT via f16 MFMA GEMM, symmetry-halved K (round 13):
//   out[b,s,t] = sum_{d=0..271} W'[s,d] * z[t,d],
//   z[t,d] = x[t+d] + x[t-d],  W'[s,d] = W[s,271+d],  W'[s,0] halved.
// Base = r10 (best, 153.4us): 4x2 frags mfma_f32_32x32x16_f16, TT=512,
// lb(256,2), fragment-ordered wpk.
// NEW vs r10: W' staged into LDS once per block (34 block-cooperative
// global_load_lds dwordx4, issued before phase A, completing under the two
// existing barriers -- zero extra sync, single copy). Rationale: wpk=34.8KB
// > 32KB L1 -> cyclic stream = ~100% L1 miss; K-loop B-loads were
// L2-latency-exposed. K-loop now has ZERO VMEM.
// r12 post-mortem: its +31us was the NONTEMPORAL stores (bypassed L2
// write-merge of the 32B/row half-line epilogue pattern -> ~2x HBM write
// traffic) + occupancy loss; plain stores here. Residency preserved:
// LDS 53.7KB x 2 blocks/CU = 107KB < 160KB at 2 waves/SIMD (190 VGPR).
// - z-frag: forward aligned ds_read_b128 (8-shifted-copy Hankel LDS) +
//   backward aligned ds_read_b128 + 8-elem reversal + v_pk_add_f16.
// - B-frag: wsm[1024*ks + 512*st + lane*8], stride-1 b128 (2-way = free).

#define TLEN  4096
#define NSC   64
#define KLEN  543
#define PADL  271
#define BLOCK 256
#define TT    512            // t per block (4 waves x 128t)
#define XSRC  1056           // raw staged x elems (132 short8)
#define XLEN  1048           // per-copy slots
#define XREG  1048           // copy stride in elems (131*8, odd chunk stride)
#define NKS2  17             // K-steps of 16 over d=0..271
#define WPK_N (NKS2 * 2 * 64 * 8)   // 17408 f16 elems = 34 x 1KB segments

typedef __attribute__((ext_vector_type(8)))  short     short8;
typedef __attribute__((ext_vector_type(8)))  _Float16  half8;
typedef __attribute__((ext_vector_type(16))) float     float16v;
typedef __attribute__((ext_vector_type(4)))  float     float4v;

__global__ __launch_bounds__(256)
void wconv(const float* __restrict__ W, _Float16* __restrict__ wpk)
{
    int idx  = blockIdx.x * 256 + threadIdx.x;    // 0..17407
    int e    = idx & 7;                           // elem within lane's 16B
    int lane = (idx >> 3) & 63;                   // hw lane order
    int st   = (idx >> 9) & 1;                    // s-frag (0: s<32, 1: s>=32)
    int ks   = idx >> 10;                         // K-step of 16 (0..16)
    int n    = lane & 31;
    int q5   = lane >> 5;
    int s    = 32 * st + n;
    int d    = 16 * ks + 8 * q5 + e;              // 0..271
    float v  = W[(size_t)s * KLEN + PADL + d];    // W'[s,d] = W[s,271+d]
    if (d == 0) v *= 0.5f;                        // absorb z[t,0] = 2*x[t]
    wpk[idx] = (_Float16)v;
}

__global__ __launch_bounds__(BLOCK, 2)
void ricker_mfma2(const float* __restrict__ x,
                  const _Float16* __restrict__ wpk,
                  float* __restrict__ out)
{
    __shared__ __align__(16) _Float16 xraw[XSRC];
    __shared__ __align__(16) _Float16 xsm[8 * XREG];   // 16768 B
    __shared__ __align__(16) _Float16 wsm[WPK_N];      // 34816 B

    const int tid    = threadIdx.x;
    const int lane   = tid & 63;
    const int wv     = tid >> 6;          // 0..3
    const int tTile  = blockIdx.x;        // 0..7
    const int b      = blockIdx.y;        // 0..127
    const int tStart = tTile * TT;

    // ---- stage W' -> LDS, block-cooperative, async (lands by barrier 2) ----
    // wave wv issues segments wv, wv+4, ...: lane l copies 16B
    // wpk[j*512 + l*8] -> wsm[j*512 + l*8] (linear dest = base + lane*16B).
    for (int j = wv; j < 2 * NKS2; j += 4) {
        __builtin_amdgcn_global_load_lds(
            (const __attribute__((address_space(1))) void*)(wpk + j * 512 + lane * 8),
            (__attribute__((address_space(3))) void*)&wsm[j * 512],
            16, 0, 0);
    }

    // ---- phase A: raw f16 x tile (halo, zero-padded), coalesced ----
    const float* xrow = x + (size_t)b * TLEN;
    for (int i = tid; i < XSRC; i += BLOCK) {
        int g = tStart - PADL + i;
        float v = (g >= 0 && g < TLEN) ? xrow[g] : 0.0f;
        xraw[i] = (_Float16)v;
    }
    __syncthreads();

    // ---- phase B: 8 shifted copies, vectorized b128 (shift c compile-time) --
    // xsm[c*XREG + p] = xraw[p + c], p in [0, XLEN), c in [0,8).
    {
        const short8* xr8 = (const short8*)xraw;
        short8*       xs8 = (short8*)xsm;
        for (int j = tid; j < 131; j += BLOCK) {      // one predicated pass
            short8 lo = xr8[j];
            short8 hi = xr8[j + 1];
            #pragma unroll
            for (int c = 0; c < 8; ++c) {
                short8 r;
                #pragma unroll
                for (int e = 0; e < 8; ++e)
                    r[e] = (c + e < 8) ? lo[c + e] : hi[c + e - 8];
                xs8[c * 131 + j] = r;                 // == xsm[c*XREG + 8j]
            }
        }
    }
    // all VMEM (x loads + W staging) must land before K-loop reads wsm/xsm
    asm volatile("s_waitcnt vmcnt(0)" ::: "memory");
    __syncthreads();

    // ---- wave GEMM: 128t x 64s, mfma_f32_32x32x16_f16, 4x2 frags ----
    const int n    = lane & 31;       // A row m / B col n / D col (s)
    const int q5   = lane >> 5;       // k-half
    const int wt0  = wv * 128;

    // Forward slab: f[j] = x[t+d0+j] = xraw[tau + 271 + d0 + j],
    //   tau = wt0+32tt+n, d0 = 16ks+8q5.  Start S_f = tau+271+d0:
    //   copy cf = (n+7)&7, in-copy slot = wt0+8q5+(n+271-cf) + 16ks+32tt.
    // Backward slab: r[e] = xraw[tau + 264 - d0 + e]  (rev(r)[j]=x[t-d0-j]):
    //   copy cr = n&7,     in-copy slot = wt0-8q5+264+(n-cr) - 16ks+32tt.
    const int cf = (n + 7) & 7;
    const int cr = n & 7;
    const _Float16* af = &xsm[cf * XREG + wt0 + 8 * q5 + (n + PADL - cf)];
    const _Float16* ar = &xsm[cr * XREG + wt0 - 8 * q5 + 264 + (n - cr)];
    // B-frag: per-(ks,st) 1KB LDS block, lane-ordered stride-1 (2-way free)
    const _Float16* bbase = wsm + lane * 8;

    float16v acc[4][2];
    #pragma unroll
    for (int tt = 0; tt < 4; ++tt)
        #pragma unroll
        for (int st = 0; st < 2; ++st)
            #pragma unroll
            for (int e = 0; e < 16; ++e) acc[tt][st][e] = 0.f;

    #pragma unroll 2
    for (int ks = 0; ks < NKS2; ++ks) {
        const int KF = 16 * ks;
        const int BO = 1024 * ks;                        // (ks*2)*512 elems
        half8 bb0 = *(const half8*)&bbase[BO];           // st=0
        half8 bb1 = *(const half8*)&bbase[BO + 512];     // st=1
        half8 z[4];
        #pragma unroll
        for (int tt = 0; tt < 4; ++tt) {
            half8 f = *(const half8*)&af[KF + 32 * tt];
            half8 r = *(const half8*)&ar[32 * tt - KF];
            half8 rv = __builtin_shufflevector(r, r, 7, 6, 5, 4, 3, 2, 1, 0);
            z[tt] = f + rv;                              // v_pk_add_f16 x4
        }
        #pragma unroll
        for (int tt = 0; tt < 4; ++tt) {
            acc[tt][0] = __builtin_amdgcn_mfma_f32_32x32x16_f16(z[tt], bb0, acc[tt][0], 0, 0, 0);
            acc[tt][1] = __builtin_amdgcn_mfma_f32_32x32x16_f16(z[tt], bb1, acc[tt][1], 0, 0, 0);
        }
    }

    // ---- epilogue: D col = n (s), row = (reg&3) + 8*(reg>>2) + 4*q5 (t) ----
    const int tb = tStart + wt0 + 4 * q5;
    float* obase = out + (size_t)b * NSC * TLEN;
    #pragma unroll
    for (int st = 0; st < 2; ++st) {
        #pragma unroll
        for (int tt = 0; tt < 4; ++tt) {
            float16v A = acc[tt][st];
            float* o = obase + (size_t)(32 * st + n) * TLEN + tb + 32 * tt;
            #pragma unroll
            for (int r4 = 0; r4 < 4; ++r4) {
                *(float4v*)&o[8 * r4] =
                    (float4v){A[4 * r4], A[4 * r4 + 1], A[4 * r4 + 2], A[4 * r4 + 3]};
            }
        }
    }
}

extern "C" void kernel_launch(void* const* d_in, const int* in_sizes, int n_in,
                              void* d_out, int out_size, void* d_ws, size_t ws_size,
                              hipStream_t stream) {
    const float* x   = (const float*)d_in[0];   // [128, 4096] fp32
    const float* W   = (const float*)d_in[1];   // [64, 543]  fp32
    float*       out = (float*)d_out;           // [128, 64, 4096] fp32
    _Float16*    wpk = (_Float16*)d_ws;         // [17,2,64,8] f16 blocks (34,816 B)

    wconv<<<dim3(WPK_N / 256), dim3(256), 0, stream>>>(W, wpk);
    dim3 grid(TLEN / TT, 128);                  // (8, 128) = 1024 blocks
    ricker_mfma2<<<grid, dim3(BLOCK), 0, stream>>>(x, wpk, out);
}